// Round 1
// baseline (148.010 us; speedup 1.0000x reference)
//
#include <hip/hip_runtime.h>
#include <hip/hip_bf16.h>
#include <math.h>
#include <stdint.h>

// Problem constants (match reference)
constexpr int Bb = 8, Nn = 4096, Kk = 32, Hh = 256;
constexpr int Mm = Bb * Nn;   // 32768 rows
constexpr int KD = 512;       // concatenated K (h | h_agg)

typedef float  f32x4 __attribute__((ext_vector_type(4)));
typedef short  s16x8 __attribute__((ext_vector_type(8)));

static __device__ __forceinline__ ushort f2bf(float f) {
  uint32_t u = __float_as_uint(f);
  u += 0x7FFF + ((u >> 16) & 1);   // round-to-nearest-even
  return (ushort)(u >> 16);
}
static __device__ __forceinline__ float bf2f(ushort s) {
  return __uint_as_float(((uint32_t)s) << 16);
}

// ---------------- idx dtype detector ----------------
// If nbr_idx is stored as int64, the high 32-bit word of every element is 0
// (values in [0,4096)). If int32, odd int32 positions hold real random values.
__global__ void detect_idx(const int* __restrict__ p, int* __restrict__ flag) {
  int t = threadIdx.x;  // 64 threads
  unsigned long long b = __ballot(p[2 * t + 1] != 0);
  if (t == 0) *flag = (b != 0ULL) ? 1 : 0;  // 1 = int32, 0 = int64
}

// ---------------- prep: h -> bf16 ----------------
__global__ __launch_bounds__(256) void prep_h(const float* __restrict__ h,
                                              ushort* __restrict__ hb) {
  int i = blockIdx.x * blockDim.x + threadIdx.x;  // exactly Mm*Hh/4 threads
  float4 v = reinterpret_cast<const float4*>(h)[i];
  ushort4 o = { f2bf(v.x), f2bf(v.y), f2bf(v.z), f2bf(v.w) };
  reinterpret_cast<ushort4*>(hb)[i] = o;
}

// ---------------- prep: W_cat = [W_self | W_neigh] bf16, row-major [256][512]
__global__ __launch_bounds__(256) void prep_w(const float* __restrict__ Ws,
                                              const float* __restrict__ Wn,
                                              ushort* __restrict__ Wc) {
  int i = blockIdx.x * blockDim.x + threadIdx.x;  // 256*512 threads
  int j = i >> 9;
  int k = i & 511;
  float v = (k < 256) ? Ws[j * 256 + k] : Wn[j * 256 + (k - 256)];
  Wc[i] = f2bf(v);
}

// ---------------- aggregate: h_agg[m] = sum_k w[m,k] * h_bf16[b, idx[m,k], :]
__global__ __launch_bounds__(256) void aggregate(const ushort* __restrict__ hb,
                                                 const void* __restrict__ idx,
                                                 const float* __restrict__ w,
                                                 ushort* __restrict__ hagg,
                                                 const int* __restrict__ flag) {
  const int wv = threadIdx.x >> 6, lane = threadIdx.x & 63;
  const int m = blockIdx.x * 4 + wv;      // one row per 64-lane wave
  const int b = m >> 12;                  // batch = m / 4096
  const int is32 = *flag;
  const float* wp = w + (size_t)m * Kk;
  const int* ip32 = (const int*)idx + (size_t)m * Kk;
  const long long* ip64 = (const long long*)idx + (size_t)m * Kk;
  const ushort4* hbb = reinterpret_cast<const ushort4*>(hb + (size_t)b * Nn * Hh);

  float4 acc = {0.f, 0.f, 0.f, 0.f};
  #pragma unroll 4
  for (int k = 0; k < Kk; ++k) {
    int r = is32 ? ip32[k] : (int)ip64[k];
    float wt = wp[k];
    ushort4 v = hbb[r * (Hh / 4) + lane];   // 512B contiguous per wave
    acc.x += wt * bf2f(v.x);
    acc.y += wt * bf2f(v.y);
    acc.z += wt * bf2f(v.z);
    acc.w += wt * bf2f(v.w);
  }
  ushort4 o = { f2bf(acc.x), f2bf(acc.y), f2bf(acc.z), f2bf(acc.w) };
  reinterpret_cast<ushort4*>(hagg)[(size_t)m * (Hh / 4) + lane] = o;
}

// ---------------- fused GEMM (K=512 concat) + GELU + LayerNorm ----------------
// Tile: BM=64 rows x BN=256 cols (full H), 4 waves, wave w owns cols [w*64, w*64+64).
// MFMA 16x16x32 bf16. LDS tiles XOR-swizzled on 16B slots: slot ^= (row & 7).
__global__ __launch_bounds__(256) void gemm_fused(const ushort* __restrict__ A0,
                                                  const ushort* __restrict__ A1,
                                                  const ushort* __restrict__ Wc,
                                                  const float* __restrict__ gamma,
                                                  const float* __restrict__ beta,
                                                  float* __restrict__ out) {
  constexpr int BM = 64, BK = 64;
  __shared__ ushort lA[BM * BK];       // 8 KB   [64 rows][64 k] (swizzled)
  __shared__ ushort lB[256 * BK];      // 32 KB  [256 rows][64 k] (swizzled)
  __shared__ float2 part[BM][4];       // per-row partial (sum, sumsq) per wave

  const int tid = threadIdx.x, wid = tid >> 6, lane = tid & 63;
  const int m0 = blockIdx.x * BM;

  f32x4 acc[4][4];
  #pragma unroll
  for (int i = 0; i < 4; ++i)
    #pragma unroll
    for (int j = 0; j < 4; ++j) acc[i][j] = f32x4{0.f, 0.f, 0.f, 0.f};

  // gamma/beta for this wave's 64 columns
  float gam[4], bet[4];
  #pragma unroll
  for (int nj = 0; nj < 4; ++nj) {
    int c = wid * 64 + nj * 16 + (lane & 15);
    gam[nj] = gamma[c];
    bet[nj] = beta[c];
  }

  for (int kt = 0; kt < KD / BK; ++kt) {
    const int k0 = kt * BK;
    const ushort* Asrc = (k0 < 256) ? (A0 + (size_t)m0 * 256 + k0)
                                    : (A1 + (size_t)m0 * 256 + (k0 - 256));
    __syncthreads();  // protect LDS from previous iteration's readers

    // Stage 40 chunks of 1KB (A: 8 chunks, B: 32 chunks), 10 per wave.
    for (int c = wid; c < 40; c += 4) {
      if (c < 8) {
        int r  = c * 8 + (lane >> 3);          // tile row 0..63
        int sl = lane & 7;                     // 16B slot (linear global read)
        s16x8 v = *reinterpret_cast<const s16x8*>(Asrc + (size_t)r * 256 + sl * 8);
        int sw = sl ^ (r & 7);
        *reinterpret_cast<s16x8*>(&lA[r * 64 + sw * 8]) = v;
      } else {
        int cb = c - 8;
        int j  = cb * 8 + (lane >> 3);         // W row 0..255
        int sl = lane & 7;
        s16x8 v = *reinterpret_cast<const s16x8*>(Wc + (size_t)j * 512 + k0 + sl * 8);
        int sw = sl ^ (j & 7);
        *reinterpret_cast<s16x8*>(&lB[j * 64 + sw * 8]) = v;
      }
    }
    __syncthreads();

    #pragma unroll
    for (int kk = 0; kk < 2; ++kk) {
      s16x8 a[4], bb[4];
      const int ks = kk * 4 + (lane >> 4);     // 16B k-slot 0..7
      #pragma unroll
      for (int mi = 0; mi < 4; ++mi) {
        int r = mi * 16 + (lane & 15);
        a[mi] = *reinterpret_cast<const s16x8*>(&lA[r * 64 + ((ks ^ (r & 7)) << 3)]);
      }
      #pragma unroll
      for (int nj = 0; nj < 4; ++nj) {
        int r = wid * 64 + nj * 16 + (lane & 15);
        bb[nj] = *reinterpret_cast<const s16x8*>(&lB[r * 64 + ((ks ^ (r & 7)) << 3)]);
      }
      #pragma unroll
      for (int mi = 0; mi < 4; ++mi)
        #pragma unroll
        for (int nj = 0; nj < 4; ++nj)
          acc[mi][nj] = __builtin_amdgcn_mfma_f32_16x16x32_bf16(a[mi], bb[nj],
                                                                acc[mi][nj], 0, 0, 0);
    }
  }

  // -------- epilogue: GELU (exact erf), then LayerNorm over the 256-col row ----
  #pragma unroll
  for (int mi = 0; mi < 4; ++mi)
    #pragma unroll
    for (int nj = 0; nj < 4; ++nj)
      #pragma unroll
      for (int jj = 0; jj < 4; ++jj) {
        float x = acc[mi][nj][jj];
        acc[mi][nj][jj] = 0.5f * x * (1.0f + erff(x * 0.7071067811865475f));
      }

  // per-row partials over this wave's 64 cols (reduce across the 16-lane col group)
  float s[4][4], q[4][4];
  #pragma unroll
  for (int mi = 0; mi < 4; ++mi)
    #pragma unroll
    for (int jj = 0; jj < 4; ++jj) {
      float sv = 0.f, qv = 0.f;
      #pragma unroll
      for (int nj = 0; nj < 4; ++nj) {
        float v = acc[mi][nj][jj];
        sv += v; qv += v * v;
      }
      #pragma unroll
      for (int msk = 8; msk >= 1; msk >>= 1) {
        sv += __shfl_xor(sv, msk, 64);
        qv += __shfl_xor(qv, msk, 64);
      }
      s[mi][jj] = sv; q[mi][jj] = qv;
    }

  if ((lane & 15) == 0) {
    #pragma unroll
    for (int mi = 0; mi < 4; ++mi)
      #pragma unroll
      for (int jj = 0; jj < 4; ++jj) {
        int r = mi * 16 + (lane >> 4) * 4 + jj;
        part[r][wid] = make_float2(s[mi][jj], q[mi][jj]);
      }
  }
  __syncthreads();

  #pragma unroll
  for (int mi = 0; mi < 4; ++mi)
    #pragma unroll
    for (int jj = 0; jj < 4; ++jj) {
      int r = mi * 16 + (lane >> 4) * 4 + jj;
      float2 p0 = part[r][0], p1 = part[r][1], p2 = part[r][2], p3 = part[r][3];
      float sm = p0.x + p1.x + p2.x + p3.x;
      float sq = p0.y + p1.y + p2.y + p3.y;
      float mean = sm * (1.0f / 256.0f);
      float var  = sq * (1.0f / 256.0f) - mean * mean;
      float inv  = rsqrtf(var + 1e-5f);
      float* orow = out + (size_t)(m0 + r) * 256;
      #pragma unroll
      for (int nj = 0; nj < 4; ++nj) {
        int c = wid * 64 + nj * 16 + (lane & 15);
        orow[c] = (acc[mi][nj][jj] - mean) * inv * gam[nj] + bet[nj];
      }
    }
}

extern "C" void kernel_launch(void* const* d_in, const int* in_sizes, int n_in,
                              void* d_out, int out_size, void* d_ws, size_t ws_size,
                              hipStream_t stream) {
  const float* h     = (const float*)d_in[0];
  const void*  idx   = d_in[1];
  const float* w     = (const float*)d_in[2];
  const float* Ws    = (const float*)d_in[3];
  const float* Wn    = (const float*)d_in[4];
  const float* gamma = (const float*)d_in[5];
  const float* beta  = (const float*)d_in[6];
  float* out = (float*)d_out;

  // workspace layout
  ushort* hb   = (ushort*)d_ws;                         // Mm*Hh bf16 = 16 MB
  ushort* hagg = hb + (size_t)Mm * Hh;                  // Mm*Hh bf16 = 16 MB
  ushort* Wc   = hagg + (size_t)Mm * Hh;                // 256*512 bf16 = 256 KB
  int* flag    = (int*)(Wc + 256 * 512);

  detect_idx<<<1, 64, 0, stream>>>((const int*)idx, flag);
  prep_h<<<(Mm * Hh / 4) / 256, 256, 0, stream>>>(h, hb);
  prep_w<<<(256 * 512) / 256, 256, 0, stream>>>(Ws, Wn, Wc);
  aggregate<<<Mm / 4, 256, 0, stream>>>(hb, idx, w, hagg, flag);
  gemm_fused<<<Mm / 64, 256, 0, stream>>>(hb, hagg, Wc, gamma, beta, out);
}

// Round 2
// 99.862 us; speedup vs baseline: 1.4821x; 1.4821x over previous
//
#include <hip/hip_runtime.h>
#include <hip/hip_bf16.h>
#include <math.h>
#include <stdint.h>

constexpr int Bb = 8, Nn = 4096, Kk = 32, Hh = 256;
constexpr int Mm = Bb * Nn;   // 32768 rows
constexpr int KD = 512;       // concatenated K (h | h_agg)

typedef float  f32x4 __attribute__((ext_vector_type(4)));
typedef short  s16x8 __attribute__((ext_vector_type(8)));

static __device__ __forceinline__ ushort f2bf(float f) {
  uint32_t u = __float_as_uint(f);
  u += 0x7FFF + ((u >> 16) & 1);
  return (ushort)(u >> 16);
}
static __device__ __forceinline__ float bf2f(ushort s) {
  return __uint_as_float(((uint32_t)s) << 16);
}

// async global->LDS, 16B per lane. LDS dest is wave-uniform base + lane*16.
static __device__ __forceinline__ void gl_lds16(const ushort* g, ushort* l) {
  __builtin_amdgcn_global_load_lds(
      (const __attribute__((address_space(1))) void*)g,
      (__attribute__((address_space(3))) void*)l, 16, 0, 0);
}

// ---------------- idx dtype detector ----------------
__global__ void detect_idx(const int* __restrict__ p, int* __restrict__ flag) {
  int t = threadIdx.x;
  unsigned long long b = __ballot(p[2 * t + 1] != 0);
  if (t == 0) *flag = (b != 0ULL) ? 1 : 0;  // 1 = int32, 0 = int64
}

// ---------------- prep: h -> bf16 ----------------
__global__ __launch_bounds__(256) void prep_h(const float* __restrict__ h,
                                              ushort* __restrict__ hb) {
  int i = blockIdx.x * blockDim.x + threadIdx.x;
  float4 v = reinterpret_cast<const float4*>(h)[i];
  ushort4 o = { f2bf(v.x), f2bf(v.y), f2bf(v.z), f2bf(v.w) };
  reinterpret_cast<ushort4*>(hb)[i] = o;
}

// ---------------- prep: W_cat = [W_self | W_neigh] bf16 [256][512] ----------
__global__ __launch_bounds__(256) void prep_w(const float* __restrict__ Ws,
                                              const float* __restrict__ Wn,
                                              ushort* __restrict__ Wc) {
  int i = blockIdx.x * blockDim.x + threadIdx.x;
  int j = i >> 9;
  int k = i & 511;
  float v = (k < 256) ? Ws[j * 256 + k] : Wn[j * 256 + (k - 256)];
  Wc[i] = f2bf(v);
}

// ---------------- aggregate (batch -> XCD pinned) ----------------
__global__ __launch_bounds__(256) void aggregate(const ushort* __restrict__ hb,
                                                 const void* __restrict__ idx,
                                                 const float* __restrict__ w,
                                                 ushort* __restrict__ hagg,
                                                 const int* __restrict__ flag) {
  const int wv = threadIdx.x >> 6, lane = threadIdx.x & 63;
  // assume round-robin block->XCD: pin batch b to XCD b so its 2MB slice L2-fits
  const int b = blockIdx.x & 7;
  const int m = b * Nn + (blockIdx.x >> 3) * 4 + wv;
  const int is32 = *flag;

  int myi; float myw;
  {
    size_t base = (size_t)m * Kk + (lane & 31);
    myi = is32 ? ((const int*)idx)[base] : (int)((const long long*)idx)[base];
    myw = w[base];
  }
  const ushort4* hbb = reinterpret_cast<const ushort4*>(hb + (size_t)b * Nn * Hh);

  float4 acc = {0.f, 0.f, 0.f, 0.f};
  #pragma unroll
  for (int k = 0; k < Kk; ++k) {
    int r    = __shfl(myi, k, 64);
    float wt = __shfl(myw, k, 64);
    ushort4 v = hbb[(size_t)r * (Hh / 4) + lane];
    acc.x += wt * bf2f(v.x);
    acc.y += wt * bf2f(v.y);
    acc.z += wt * bf2f(v.z);
    acc.w += wt * bf2f(v.w);
  }
  ushort4 o = { f2bf(acc.x), f2bf(acc.y), f2bf(acc.z), f2bf(acc.w) };
  reinterpret_cast<ushort4*>(hagg)[(size_t)m * (Hh / 4) + lane] = o;
}

// ---------------- fused GEMM + GELU + LayerNorm ----------------
// BM=128 x BN=256, BK=32, 4 waves, wave tile 64x128 (acc[4][8]).
// Double-buffered LDS, async global_load_lds with pre-swizzled source:
// 16B slot s' = s ^ ((row>>1)&3)  (bank permutation for 64B rows, involution).
__global__ __launch_bounds__(256, 1) void gemm_fused(
    const ushort* __restrict__ A0, const ushort* __restrict__ A1,
    const ushort* __restrict__ Wc, const float* __restrict__ gamma,
    const float* __restrict__ beta, float* __restrict__ out) {
  constexpr int BM = 128, BK = 32, NKT = KD / BK;  // 16 K-steps
  __shared__ ushort lA[2][BM * BK];    // 2 x 8 KB
  __shared__ ushort lB[2][256 * BK];   // 2 x 16 KB
  __shared__ float2 part[BM][2];       // 2 KB

  const int tid = threadIdx.x, wid = tid >> 6, lane = tid & 63;
  const int wr = wid >> 1, wc = wid & 1;   // wave tile: rows wr*64.., cols wc*128..
  const int m0 = blockIdx.x * BM;

  f32x4 acc[4][8];
  #pragma unroll
  for (int i = 0; i < 4; ++i)
    #pragma unroll
    for (int j = 0; j < 8; ++j) acc[i][j] = f32x4{0.f, 0.f, 0.f, 0.f};

  float gam[8], bet[8];
  #pragma unroll
  for (int nj = 0; nj < 8; ++nj) {
    int c = wc * 128 + nj * 16 + (lane & 15);
    gam[nj] = gamma[c];
    bet[nj] = beta[c];
  }

  // staging lambdas: 1KB chunks (16 rows x 64B), per-lane pre-swizzled source
  const int crow = lane >> 2;          // row within chunk 0..15
  const int cslot = lane & 3;          // LDS 16B slot within row
  auto stage = [&](int buf, int kt) {
    const int k0 = kt * BK;
    const ushort* Asrc = (k0 < 256) ? (A0 + (size_t)m0 * 256 + k0)
                                    : (A1 + (size_t)m0 * 256 + (k0 - 256));
    #pragma unroll
    for (int c = 0; c < 2; ++c) {      // A: 8 chunks / 4 waves
      int ch = wid + c * 4;
      int r = ch * 16 + crow;
      int s = cslot ^ ((r >> 1) & 3);
      gl_lds16(Asrc + (size_t)r * 256 + s * 8, &lA[buf][ch * 512]);
    }
    #pragma unroll
    for (int c = 0; c < 4; ++c) {      // B: 16 chunks / 4 waves
      int ch = wid + c * 4;
      int r = ch * 16 + crow;
      int s = cslot ^ ((r >> 1) & 3);
      gl_lds16(Wc + (size_t)r * 512 + k0 + s * 8, &lB[buf][ch * 512]);
    }
  };

  int cur = 0;
  stage(0, 0);
  __syncthreads();

  for (int kt = 0; kt < NKT; ++kt) {
    if (kt + 1 < NKT) stage(cur ^ 1, kt + 1);   // async prefetch

    const int ks = lane >> 4;
    s16x8 a[4], b[8];
    #pragma unroll
    for (int mi = 0; mi < 4; ++mi) {
      int r = wr * 64 + mi * 16 + (lane & 15);
      a[mi] = *reinterpret_cast<const s16x8*>(
          &lA[cur][r * BK + ((ks ^ ((r >> 1) & 3)) << 3)]);
    }
    #pragma unroll
    for (int nj = 0; nj < 8; ++nj) {
      int r = wc * 128 + nj * 16 + (lane & 15);
      b[nj] = *reinterpret_cast<const s16x8*>(
          &lB[cur][r * BK + ((ks ^ ((r >> 1) & 3)) << 3)]);
    }
    #pragma unroll
    for (int mi = 0; mi < 4; ++mi)
      #pragma unroll
      for (int nj = 0; nj < 8; ++nj)
        acc[mi][nj] = __builtin_amdgcn_mfma_f32_16x16x32_bf16(a[mi], b[nj],
                                                              acc[mi][nj], 0, 0, 0);
    __syncthreads();   // drains prefetch vmcnt + protects both buffers
    cur ^= 1;
  }

  // -------- epilogue: GELU then LayerNorm over 256-col rows --------
  #pragma unroll
  for (int mi = 0; mi < 4; ++mi)
    #pragma unroll
    for (int nj = 0; nj < 8; ++nj)
      #pragma unroll
      for (int jj = 0; jj < 4; ++jj) {
        float x = acc[mi][nj][jj];
        acc[mi][nj][jj] = 0.5f * x * (1.0f + erff(x * 0.7071067811865475f));
      }

  float s[4][4], q[4][4];
  #pragma unroll
  for (int mi = 0; mi < 4; ++mi)
    #pragma unroll
    for (int jj = 0; jj < 4; ++jj) {
      float sv = 0.f, qv = 0.f;
      #pragma unroll
      for (int nj = 0; nj < 8; ++nj) {
        float v = acc[mi][nj][jj];
        sv += v; qv += v * v;
      }
      #pragma unroll
      for (int msk = 8; msk >= 1; msk >>= 1) {
        sv += __shfl_xor(sv, msk, 64);
        qv += __shfl_xor(qv, msk, 64);
      }
      s[mi][jj] = sv; q[mi][jj] = qv;
    }

  if ((lane & 15) == 0) {
    #pragma unroll
    for (int mi = 0; mi < 4; ++mi)
      #pragma unroll
      for (int jj = 0; jj < 4; ++jj) {
        int r = wr * 64 + mi * 16 + (lane >> 4) * 4 + jj;
        part[r][wc] = make_float2(s[mi][jj], q[mi][jj]);
      }
  }
  __syncthreads();

  #pragma unroll
  for (int mi = 0; mi < 4; ++mi)
    #pragma unroll
    for (int jj = 0; jj < 4; ++jj) {
      int r = wr * 64 + mi * 16 + (lane >> 4) * 4 + jj;
      float2 p0 = part[r][0], p1 = part[r][1];
      float sm = p0.x + p1.x;
      float sq = p0.y + p1.y;
      float mean = sm * (1.0f / 256.0f);
      float var  = sq * (1.0f / 256.0f) - mean * mean;
      float inv  = rsqrtf(var + 1e-5f);
      float* orow = out + (size_t)(m0 + r) * 256;
      #pragma unroll
      for (int nj = 0; nj < 8; ++nj) {
        int c = wc * 128 + nj * 16 + (lane & 15);
        orow[c] = (acc[mi][nj][jj] - mean) * inv * gam[nj] + bet[nj];
      }
    }
}

extern "C" void kernel_launch(void* const* d_in, const int* in_sizes, int n_in,
                              void* d_out, int out_size, void* d_ws, size_t ws_size,
                              hipStream_t stream) {
  const float* h     = (const float*)d_in[0];
  const void*  idx   = d_in[1];
  const float* w     = (const float*)d_in[2];
  const float* Ws    = (const float*)d_in[3];
  const float* Wn    = (const float*)d_in[4];
  const float* gamma = (const float*)d_in[5];
  const float* beta  = (const float*)d_in[6];
  float* out = (float*)d_out;

  ushort* hb   = (ushort*)d_ws;
  ushort* hagg = hb + (size_t)Mm * Hh;
  ushort* Wc   = hagg + (size_t)Mm * Hh;
  int* flag    = (int*)(Wc + 256 * 512);

  detect_idx<<<1, 64, 0, stream>>>((const int*)idx, flag);
  prep_h<<<(Mm * Hh / 4) / 256, 256, 0, stream>>>(h, hb);
  prep_w<<<(256 * 512) / 256, 256, 0, stream>>>(Ws, Wn, Wc);
  aggregate<<<Mm / 4, 256, 0, stream>>>(hb, idx, w, hagg, flag);
  gemm_fused<<<Mm / 128, 256, 0, stream>>>(hb, hagg, Wc, gamma, beta, out);
}

// Round 3
// 66.841 us; speedup vs baseline: 2.2144x; 1.4940x over previous
//
#include <hip/hip_runtime.h>
#include <hip/hip_bf16.h>
#include <math.h>
#include <stdint.h>

constexpr int Nn = 4096, Kk = 32, Hh = 256;
constexpr int Mm = 8 * Nn;          // 32768 rows

typedef float  f32x4 __attribute__((ext_vector_type(4)));
typedef short  s16x8 __attribute__((ext_vector_type(8)));

static __device__ __forceinline__ ushort f2bf(float f) {
  uint32_t u = __float_as_uint(f);
  u += 0x7FFF + ((u >> 16) & 1);
  return (ushort)(u >> 16);
}
static __device__ __forceinline__ float bf2f(ushort s) {
  return __uint_as_float(((uint32_t)s) << 16);
}
static __device__ __forceinline__ void gl_lds16(const ushort* g, ushort* l) {
  __builtin_amdgcn_global_load_lds(
      (const __attribute__((address_space(1))) void*)g,
      (__attribute__((address_space(3))) void*)l, 16, 0, 0);
}
// gelu(x) ~= x - x/(e^y + 1),  y = x*(2c + 2c*0.044715*x^2), c = 0.79788456
static __device__ __forceinline__ float gelu_t(float x) {
  float u = x * x;
  float y = x * (1.5957691216f + 0.0713548162726f * u);
  float t = __expf(y);
  return x - x * __builtin_amdgcn_rcpf(t + 1.0f);
}

// ---------------- idx dtype detector ----------------
__global__ void detect_idx(const int* __restrict__ p, int* __restrict__ flag) {
  int t = threadIdx.x;
  unsigned long long b = __ballot(p[2 * t + 1] != 0);
  if (t == 0) *flag = (b != 0ULL) ? 1 : 0;  // 1 = int32, 0 = int64
}

// ---------------- prep: Wcat = [Ws; Wn] bf16, row-major [512][256] ----------
__global__ __launch_bounds__(256) void prep_w(const float* __restrict__ Ws,
                                              const float* __restrict__ Wn,
                                              ushort* __restrict__ Wc) {
  int i = blockIdx.x * 256 + threadIdx.x;      // 32768 threads, 4 elems each
  int j  = i >> 6;
  int k4 = i & 63;
  const float* src = (j < 256) ? (Ws + (size_t)j * 256 + k4 * 4)
                               : (Wn + (size_t)(j - 256) * 256 + k4 * 4);
  float4 v = *reinterpret_cast<const float4*>(src);
  ushort4 o = { f2bf(v.x), f2bf(v.y), f2bf(v.z), f2bf(v.w) };
  reinterpret_cast<ushort4*>(Wc)[i] = o;
}

// ---------------- gemm1: [hs|hn] = h @ Wcat^T, bf16 out, no epilogue -------
// M=32768 K=256, per block BM=64 x BN=256, BK=64, 8 waves, wave-tile 16x128.
// A reg-staged from fp32 h (cvt->ds_write, swizzled); B via global_load_lds
// with pre-swizzled source. Double buffered. Batch->XCD pinned.
__global__ __launch_bounds__(512, 4) void gemm1(const float* __restrict__ h,
                                                const ushort* __restrict__ Wc,
                                                ushort* __restrict__ hs,
                                                ushort* __restrict__ hn) {
  __shared__ ushort lA[2][64 * 64];    // 2 x 8 KB
  __shared__ ushort lB[2][256 * 64];   // 2 x 32 KB
  const int tid = threadIdx.x, wid = tid >> 6, lane = tid & 63;
  const int wr = wid >> 1, wc = wid & 1;

  const int blk = blockIdx.x;
  const int b = blk & 7, t = blk >> 3;
  const int nblk = t & 1, mblk = t >> 1;
  const int m0 = b * Nn + mblk * 64;
  const ushort* Wbase = Wc + (size_t)nblk * 256 * 256;

  f32x4 acc[8];
  #pragma unroll
  for (int j = 0; j < 8; ++j) acc[j] = f32x4{0.f, 0.f, 0.f, 0.f};

  float4 a0, a1;
  const int ar = tid >> 3, as = tid & 7;             // A stage: row, slot
  auto aload = [&](int kt) {
    const float* src = h + (size_t)(m0 + ar) * 256 + kt * 64 + as * 8;
    a0 = *reinterpret_cast<const float4*>(src);
    a1 = *reinterpret_cast<const float4*>(src + 4);
  };
  auto awrite = [&](int buf) {
    s16x8 u = { (short)f2bf(a0.x), (short)f2bf(a0.y), (short)f2bf(a0.z),
                (short)f2bf(a0.w), (short)f2bf(a1.x), (short)f2bf(a1.y),
                (short)f2bf(a1.z), (short)f2bf(a1.w) };
    *reinterpret_cast<s16x8*>(&lA[buf][ar * 64 + ((as ^ (ar & 7)) << 3)]) = u;
  };
  auto bstage = [&](int buf, int kt) {
    #pragma unroll
    for (int c = 0; c < 4; ++c) {
      int ch = wid + c * 8;
      int r = ch * 8 + (lane >> 3);
      int s = (lane & 7) ^ (r & 7);
      gl_lds16(Wbase + (size_t)r * 256 + kt * 64 + s * 8, &lB[buf][ch * 512]);
    }
  };

  aload(0);
  bstage(0, 0);
  awrite(0);
  __syncthreads();

  int buf = 0;
  for (int kt = 0; kt < 4; ++kt) {
    if (kt < 3) { aload(kt + 1); bstage(buf ^ 1, kt + 1); }
    #pragma unroll
    for (int kk = 0; kk < 2; ++kk) {
      const int ks = kk * 4 + (lane >> 4);
      const int ra = wr * 16 + (lane & 15);
      s16x8 af = *reinterpret_cast<const s16x8*>(
          &lA[buf][ra * 64 + ((ks ^ (ra & 7)) << 3)]);
      s16x8 bfr[8];
      #pragma unroll
      for (int nj = 0; nj < 8; ++nj) {
        int rb = wc * 128 + nj * 16 + (lane & 15);
        bfr[nj] = *reinterpret_cast<const s16x8*>(
            &lB[buf][rb * 64 + ((ks ^ (rb & 7)) << 3)]);
      }
      #pragma unroll
      for (int nj = 0; nj < 8; ++nj)
        acc[nj] = __builtin_amdgcn_mfma_f32_16x16x32_bf16(af, bfr[nj],
                                                          acc[nj], 0, 0, 0);
    }
    if (kt < 3) awrite(buf ^ 1);
    __syncthreads();
    buf ^= 1;
  }

  ushort* dst = (nblk == 0) ? hs : hn;
  #pragma unroll
  for (int nj = 0; nj < 8; ++nj)
    #pragma unroll
    for (int jj = 0; jj < 4; ++jj) {
      int row = wr * 16 + (lane >> 4) * 4 + jj;
      int col = wc * 128 + nj * 16 + (lane & 15);
      dst[(size_t)(m0 + row) * 256 + col] = f2bf(acc[nj][jj]);
    }
}

// ---------------- k2: out = LN(gelu(hs[m] + sum_k w * hn[idx_k])) ----------
// One row per wave, 4 waves/block, batch->XCD pinned gathers (512B rows).
__global__ __launch_bounds__(256, 4) void k2(const ushort* __restrict__ hs,
                                             const ushort* __restrict__ hn,
                                             const void* __restrict__ idx,
                                             const float* __restrict__ w,
                                             const float* __restrict__ gamma,
                                             const float* __restrict__ beta,
                                             float* __restrict__ out,
                                             const int* __restrict__ flag) {
  const int wv = threadIdx.x >> 6, lane = threadIdx.x & 63;
  const int b = blockIdx.x & 7;
  const int m = b * Nn + (blockIdx.x >> 3) * 4 + wv;
  const int is32 = *flag;

  size_t kbase = (size_t)m * Kk + (lane & 31);
  int myi = is32 ? ((const int*)idx)[kbase] : (int)((const long long*)idx)[kbase];
  float myw = w[kbase];

  const ushort4* hs4 = reinterpret_cast<const ushort4*>(hs);
  const ushort4* hn4 = reinterpret_cast<const ushort4*>(hn) + (size_t)b * Nn * 64;

  float4 acc;
  {
    ushort4 v = hs4[(size_t)m * 64 + lane];
    acc.x = bf2f(v.x); acc.y = bf2f(v.y); acc.z = bf2f(v.z); acc.w = bf2f(v.w);
  }
  #pragma unroll
  for (int k = 0; k < Kk; ++k) {
    int r    = __shfl(myi, k, 64);
    float wt = __shfl(myw, k, 64);
    ushort4 v = hn4[(size_t)r * 64 + lane];
    acc.x += wt * bf2f(v.x);
    acc.y += wt * bf2f(v.y);
    acc.z += wt * bf2f(v.z);
    acc.w += wt * bf2f(v.w);
  }

  float g0 = gelu_t(acc.x), g1 = gelu_t(acc.y), g2 = gelu_t(acc.z), g3 = gelu_t(acc.w);
  float sv = g0 + g1 + g2 + g3;
  float qv = g0 * g0 + g1 * g1 + g2 * g2 + g3 * g3;
  #pragma unroll
  for (int msk = 32; msk >= 1; msk >>= 1) {
    sv += __shfl_xor(sv, msk, 64);
    qv += __shfl_xor(qv, msk, 64);
  }
  float mean = sv * (1.0f / 256.0f);
  float var  = qv * (1.0f / 256.0f) - mean * mean;
  float inv  = rsqrtf(var + 1e-5f);

  float4 gm = reinterpret_cast<const float4*>(gamma)[lane];
  float4 bt = reinterpret_cast<const float4*>(beta)[lane];
  float4 o;
  o.x = (g0 - mean) * inv * gm.x + bt.x;
  o.y = (g1 - mean) * inv * gm.y + bt.y;
  o.z = (g2 - mean) * inv * gm.z + bt.z;
  o.w = (g3 - mean) * inv * gm.w + bt.w;
  reinterpret_cast<float4*>(out)[(size_t)m * 64 + lane] = o;
}

extern "C" void kernel_launch(void* const* d_in, const int* in_sizes, int n_in,
                              void* d_out, int out_size, void* d_ws, size_t ws_size,
                              hipStream_t stream) {
  const float* h     = (const float*)d_in[0];
  const void*  idx   = d_in[1];
  const float* w     = (const float*)d_in[2];
  const float* Ws    = (const float*)d_in[3];
  const float* Wn    = (const float*)d_in[4];
  const float* gamma = (const float*)d_in[5];
  const float* beta  = (const float*)d_in[6];
  float* out = (float*)d_out;

  ushort* hs = (ushort*)d_ws;                       // 16 MB
  ushort* hn = hs + (size_t)Mm * Hh;                // 16 MB
  ushort* Wc = hn + (size_t)Mm * Hh;                // 256 KB
  int* flag  = (int*)(Wc + 512 * 256);

  detect_idx<<<1, 64, 0, stream>>>((const int*)idx, flag);
  prep_w<<<128, 256, 0, stream>>>(Ws, Wn, Wc);
  gemm1<<<1024, 512, 0, stream>>>(h, Wc, hs, hn);
  k2<<<Mm / 4, 256, 0, stream>>>(hs, hn, idx, w, gamma, beta, out, flag);
}

// Round 4
// 60.445 us; speedup vs baseline: 2.4487x; 1.1058x over previous
//
#include <hip/hip_runtime.h>
#include <hip/hip_bf16.h>
#include <math.h>
#include <stdint.h>

constexpr int Nn = 4096, Kk = 32, Hh = 256;
constexpr int Mm = 8 * Nn;          // 32768 rows

typedef float  f32x4 __attribute__((ext_vector_type(4)));
typedef short  s16x8 __attribute__((ext_vector_type(8)));

static __device__ __forceinline__ ushort f2bf(float f) {
  uint32_t u = __float_as_uint(f);
  u += 0x7FFF + ((u >> 16) & 1);
  return (ushort)(u >> 16);
}
static __device__ __forceinline__ float bf2f(ushort s) {
  return __uint_as_float(((uint32_t)s) << 16);
}
static __device__ __forceinline__ void gl_lds16(const ushort* g, ushort* l) {
  __builtin_amdgcn_global_load_lds(
      (const __attribute__((address_space(1))) void*)g,
      (__attribute__((address_space(3))) void*)l, 16, 0, 0);
}
// gelu(x) ~= x - x/(e^y + 1),  y = x*(2c + 2c*0.044715*x^2), c = 0.79788456
static __device__ __forceinline__ float gelu_t(float x) {
  float u = x * x;
  float y = x * (1.5957691216f + 0.0713548162726f * u);
  float t = __expf(y);
  return x - x * __builtin_amdgcn_rcpf(t + 1.0f);
}

// ---------------- idx dtype detector ----------------
__global__ void detect_idx(const int* __restrict__ p, int* __restrict__ flag) {
  int t = threadIdx.x;
  unsigned long long b = __ballot(p[2 * t + 1] != 0);
  if (t == 0) *flag = (b != 0ULL) ? 1 : 0;  // 1 = int32, 0 = int64
}

// ---------------- prep: Wcat = [Ws; Wn] bf16, row-major [512][256] ----------
__global__ __launch_bounds__(256) void prep_w(const float* __restrict__ Ws,
                                              const float* __restrict__ Wn,
                                              ushort* __restrict__ Wc) {
  int i = blockIdx.x * 256 + threadIdx.x;      // 32768 threads, 4 elems each
  int j  = i >> 6;
  int k4 = i & 63;
  const float* src = (j < 256) ? (Ws + (size_t)j * 256 + k4 * 4)
                               : (Wn + (size_t)(j - 256) * 256 + k4 * 4);
  float4 v = *reinterpret_cast<const float4*>(src);
  ushort4 o = { f2bf(v.x), f2bf(v.y), f2bf(v.z), f2bf(v.w) };
  reinterpret_cast<ushort4*>(Wc)[i] = o;
}

// ---------------- gemm1: [hs|hn] = h @ Wcat^T, bf16 out, no epilogue -------
__global__ __launch_bounds__(512, 4) void gemm1(const float* __restrict__ h,
                                                const ushort* __restrict__ Wc,
                                                ushort* __restrict__ hs,
                                                ushort* __restrict__ hn) {
  __shared__ ushort lA[2][64 * 64];    // 2 x 8 KB
  __shared__ ushort lB[2][256 * 64];   // 2 x 32 KB
  const int tid = threadIdx.x, wid = tid >> 6, lane = tid & 63;
  const int wr = wid >> 1, wc = wid & 1;

  const int blk = blockIdx.x;
  const int b = blk & 7, t = blk >> 3;
  const int nblk = t & 1, mblk = t >> 1;
  const int m0 = b * Nn + mblk * 64;
  const ushort* Wbase = Wc + (size_t)nblk * 256 * 256;

  f32x4 acc[8];
  #pragma unroll
  for (int j = 0; j < 8; ++j) acc[j] = f32x4{0.f, 0.f, 0.f, 0.f};

  float4 a0, a1;
  const int ar = tid >> 3, as = tid & 7;             // A stage: row, slot
  auto aload = [&](int kt) {
    const float* src = h + (size_t)(m0 + ar) * 256 + kt * 64 + as * 8;
    a0 = *reinterpret_cast<const float4*>(src);
    a1 = *reinterpret_cast<const float4*>(src + 4);
  };
  auto awrite = [&](int buf) {
    s16x8 u = { (short)f2bf(a0.x), (short)f2bf(a0.y), (short)f2bf(a0.z),
                (short)f2bf(a0.w), (short)f2bf(a1.x), (short)f2bf(a1.y),
                (short)f2bf(a1.z), (short)f2bf(a1.w) };
    *reinterpret_cast<s16x8*>(&lA[buf][ar * 64 + ((as ^ (ar & 7)) << 3)]) = u;
  };
  auto bstage = [&](int buf, int kt) {
    #pragma unroll
    for (int c = 0; c < 4; ++c) {
      int ch = wid + c * 8;
      int r = ch * 8 + (lane >> 3);
      int s = (lane & 7) ^ (r & 7);
      gl_lds16(Wbase + (size_t)r * 256 + kt * 64 + s * 8, &lB[buf][ch * 512]);
    }
  };

  aload(0);
  bstage(0, 0);
  awrite(0);
  __syncthreads();

  int buf = 0;
  for (int kt = 0; kt < 4; ++kt) {
    if (kt < 3) { aload(kt + 1); bstage(buf ^ 1, kt + 1); }
    #pragma unroll
    for (int kk = 0; kk < 2; ++kk) {
      const int ks = kk * 4 + (lane >> 4);
      const int ra = wr * 16 + (lane & 15);
      s16x8 af = *reinterpret_cast<const s16x8*>(
          &lA[buf][ra * 64 + ((ks ^ (ra & 7)) << 3)]);
      s16x8 bfr[8];
      #pragma unroll
      for (int nj = 0; nj < 8; ++nj) {
        int rb = wc * 128 + nj * 16 + (lane & 15);
        bfr[nj] = *reinterpret_cast<const s16x8*>(
            &lB[buf][rb * 64 + ((ks ^ (rb & 7)) << 3)]);
      }
      #pragma unroll
      for (int nj = 0; nj < 8; ++nj)
        acc[nj] = __builtin_amdgcn_mfma_f32_16x16x32_bf16(af, bfr[nj],
                                                          acc[nj], 0, 0, 0);
    }
    if (kt < 3) awrite(buf ^ 1);
    __syncthreads();
    buf ^= 1;
  }

  ushort* dst = (nblk == 0) ? hs : hn;
  #pragma unroll
  for (int nj = 0; nj < 8; ++nj)
    #pragma unroll
    for (int jj = 0; jj < 4; ++jj) {
      int row = wr * 16 + (lane >> 4) * 4 + jj;
      int col = wc * 128 + nj * 16 + (lane & 15);
      dst[(size_t)(m0 + row) * 256 + col] = f2bf(acc[nj][jj]);
    }
}

// ---------------- k2: out = LN(gelu(hs[m] + sum_k w * hn[idx_k])) ----------
// One row per HALF-wave (16 B/lane), 4-deep named prefetch, dual acc banks.
__global__ __launch_bounds__(512, 4) void k2(const ushort* __restrict__ hs,
                                             const ushort* __restrict__ hn,
                                             const void* __restrict__ idx,
                                             const float* __restrict__ w,
                                             const float* __restrict__ gamma,
                                             const float* __restrict__ beta,
                                             float* __restrict__ out,
                                             const int* __restrict__ flag) {
  const int tid = threadIdx.x, wv = tid >> 6, lane = tid & 63;
  const int hw = lane >> 5, l5 = lane & 31;
  const int b = blockIdx.x & 7;                       // batch -> XCD pin
  const int m = b * Nn + (blockIdx.x >> 3) * 16 + wv * 2 + hw;
  const int is32 = *flag;

  size_t kb = (size_t)m * Kk + l5;                    // lane l5 owns idx/w[k=l5]
  int   myi = is32 ? ((const int*)idx)[kb] : (int)((const long long*)idx)[kb];
  float myw = w[kb];

  const ushort* hnb = hn + (size_t)b * Nn * Hh;

  auto ld = [&](int k) -> s16x8 {
    int r = __shfl(myi, k, 32);
    return *reinterpret_cast<const s16x8*>(hnb + ((size_t)r << 8) + (l5 << 3));
  };

  f32x4 aA0{0,0,0,0}, aA1{0,0,0,0}, aB0{0,0,0,0}, aB1{0,0,0,0};
  s16x8 p0 = ld(0), p1 = ld(1), p2 = ld(2), p3 = ld(3);

  #pragma unroll
  for (int k = 0; k < 32; k += 4) {
    float w0 = __shfl(myw, k, 32),     w1 = __shfl(myw, k + 1, 32);
    float w2 = __shfl(myw, k + 2, 32), w3 = __shfl(myw, k + 3, 32);
    s16x8 q0 = p0, q1 = p1, q2 = p2, q3 = p3;
    if (k + 4 < 32) { p0 = ld(k + 4); p1 = ld(k + 5); p2 = ld(k + 6); p3 = ld(k + 7); }
    #pragma unroll
    for (int j = 0; j < 4; ++j) {
      aA0[j] += w0 * bf2f((ushort)q0[j]);
      aA1[j] += w0 * bf2f((ushort)q0[j + 4]);
      aA0[j] += w1 * bf2f((ushort)q1[j]);
      aA1[j] += w1 * bf2f((ushort)q1[j + 4]);
      aB0[j] += w2 * bf2f((ushort)q2[j]);
      aB1[j] += w2 * bf2f((ushort)q2[j + 4]);
      aB0[j] += w3 * bf2f((ushort)q3[j]);
      aB1[j] += w3 * bf2f((ushort)q3[j + 4]);
    }
  }

  // add self term, GELU
  s16x8 hv = *reinterpret_cast<const s16x8*>(hs + (size_t)m * Hh + l5 * 8);
  float g[8];
  #pragma unroll
  for (int j = 0; j < 4; ++j) {
    g[j]     = gelu_t(aA0[j] + aB0[j] + bf2f((ushort)hv[j]));
    g[j + 4] = gelu_t(aA1[j] + aB1[j] + bf2f((ushort)hv[j + 4]));
  }

  float sv = 0.f, qv = 0.f;
  #pragma unroll
  for (int j = 0; j < 8; ++j) { sv += g[j]; qv += g[j] * g[j]; }
  #pragma unroll
  for (int msk = 16; msk >= 1; msk >>= 1) {   // reduce within the 32-lane half
    sv += __shfl_xor(sv, msk, 64);
    qv += __shfl_xor(qv, msk, 64);
  }
  float mean = sv * (1.0f / 256.0f);
  float var  = qv * (1.0f / 256.0f) - mean * mean;
  float inv  = rsqrtf(var + 1e-5f);

  float4 gm0 = reinterpret_cast<const float4*>(gamma)[l5 * 2];
  float4 gm1 = reinterpret_cast<const float4*>(gamma)[l5 * 2 + 1];
  float4 bt0 = reinterpret_cast<const float4*>(beta)[l5 * 2];
  float4 bt1 = reinterpret_cast<const float4*>(beta)[l5 * 2 + 1];
  float4 o0, o1;
  o0.x = (g[0] - mean) * inv * gm0.x + bt0.x;
  o0.y = (g[1] - mean) * inv * gm0.y + bt0.y;
  o0.z = (g[2] - mean) * inv * gm0.z + bt0.z;
  o0.w = (g[3] - mean) * inv * gm0.w + bt0.w;
  o1.x = (g[4] - mean) * inv * gm1.x + bt1.x;
  o1.y = (g[5] - mean) * inv * gm1.y + bt1.y;
  o1.z = (g[6] - mean) * inv * gm1.z + bt1.z;
  o1.w = (g[7] - mean) * inv * gm1.w + bt1.w;
  float4* op = reinterpret_cast<float4*>(out + (size_t)m * Hh + l5 * 8);
  op[0] = o0;
  op[1] = o1;
}

extern "C" void kernel_launch(void* const* d_in, const int* in_sizes, int n_in,
                              void* d_out, int out_size, void* d_ws, size_t ws_size,
                              hipStream_t stream) {
  const float* h     = (const float*)d_in[0];
  const void*  idx   = d_in[1];
  const float* w     = (const float*)d_in[2];
  const float* Ws    = (const float*)d_in[3];
  const float* Wn    = (const float*)d_in[4];
  const float* gamma = (const float*)d_in[5];
  const float* beta  = (const float*)d_in[6];
  float* out = (float*)d_out;

  ushort* hs = (ushort*)d_ws;                       // 16 MB
  ushort* hn = hs + (size_t)Mm * Hh;                // 16 MB
  ushort* Wc = hn + (size_t)Mm * Hh;                // 256 KB
  int* flag  = (int*)(Wc + 512 * 256);

  detect_idx<<<1, 64, 0, stream>>>((const int*)idx, flag);
  prep_w<<<128, 256, 0, stream>>>(Ws, Wn, Wc);
  gemm1<<<1024, 512, 0, stream>>>(h, Wc, hs, hn);
  k2<<<2048, 512, 0, stream>>>(hs, hn, idx, w, gamma, beta, out, flag);
}